// Round 6
// baseline (637.408 us; speedup 1.0000x reference)
//
#include <hip/hip_runtime.h>
#include <math.h>
#include <float.h>
#include <limits.h>
#include <stdint.h>

namespace {

constexpr int B  = 2;
constexpr int CK = 64;
constexpr int N  = 12960;   // T*H*W = 8*30*54
constexpr int M  = 1620;    // H*W = 30*54
constexpr int CV = 384;
constexpr int K  = 20;      // topk (setup fixed)

// segmented fused top-k geometry
constexpr int SEGN  = 1024;                    // n covered per stage-1 block
constexpr int NSEG  = (N + SEGN - 1) / SEGN;   // 13 segments
constexpr int CAP   = 64;                      // candidate slots per (m, seg); mean ~24, +8 sigma safe
constexpr int SLOTS = NSEG * CAP;              // 832 slots per (b, m)
constexpr int JC    = (SLOTS + 255) / 256;     // 4 candidate slots per thread in merge
constexpr int MG    = (M + 15) / 16;           // 102 m-groups

static_assert((CAP & (CAP - 1)) == 0, "CAP must be pow2 (slot>>6 indexing)");
static_assert(NSEG * SEGN >= N, "segments must cover N");

// monotone float->uint key (order-preserving) and inverse
__device__ __forceinline__ uint32_t f2k(float x) {
  uint32_t u = __float_as_uint(x);
  return u ^ ((u & 0x80000000u) ? 0xFFFFFFFFu : 0x80000000u);
}
__device__ __forceinline__ float k2f(uint32_t k) {
  uint32_t u = (k & 0x80000000u) ? (k ^ 0x80000000u) : ~k;
  return __uint_as_float(u);
}

// K0: mvT[b][n][c] = mv[b][c][n]  (so gather reads are contiguous in c)
__global__ __launch_bounds__(256) void transpose_kernel(const float* __restrict__ mv,
                                                        float* __restrict__ mvT) {
  __shared__ float tile[64][65];
  int b = blockIdx.z;
  int n0 = blockIdx.x * 64;
  int c0 = blockIdx.y * 64;
  int tx = threadIdx.x & 63, ty = threadIdx.x >> 6;
  for (int r = ty; r < 64; r += 4) {
    int c = c0 + r, n = n0 + tx;
    tile[r][tx] = (n < N) ? mv[((size_t)b * CV + c) * N + n] : 0.f;
  }
  __syncthreads();
  for (int r = ty; r < 64; r += 4) {
    int n = n0 + r, c = c0 + tx;
    if (n < N) mvT[((size_t)b * N + n) * CV + c] = tile[tx][r];
  }
}

// K5: out[b][c][m] = outT[b][m][c]
__global__ __launch_bounds__(256) void transpose_out_kernel(const float* __restrict__ outT,
                                                            float* __restrict__ out) {
  __shared__ float tile[64][65];
  int b = blockIdx.z;
  int m0 = blockIdx.x * 64;
  int c0 = blockIdx.y * 64;
  int tx = threadIdx.x & 63, ty = threadIdx.x >> 6;
  for (int r = ty; r < 64; r += 4) {
    int m = m0 + r;
    if (m < M) tile[r][tx] = outT[((size_t)b * M + m) * CV + c0 + tx];
  }
  __syncthreads();
  for (int r = ty; r < 64; r += 4) {
    int c = c0 + r, m = m0 + tx;
    if (m < M) out[((size_t)b * CV + c) * M + m] = tile[tx][r];
  }
}

// K1: a_sq[b,n] = sum_c mk[b,c,n]^2
__global__ __launch_bounds__(256) void asq_kernel(const float* __restrict__ mk,
                                                  float* __restrict__ asq) {
  int i = blockIdx.x * 256 + threadIdx.x;
  if (i >= B * N) return;
  int b = i / N, n = i - b * N;
  const float* p = mk + (size_t)b * CK * N + n;
  float s = 0.f;
#pragma unroll
  for (int c = 0; c < CK; ++c) {
    float v = p[(size_t)c * N];
    s += v * v;
  }
  asq[i] = s;
}

// K2 (fused, wave-per-chunk): block = 16 m x 1024 n. Wave w owns n-chunk w
// (256 n) for ALL 16 m -> per c each thread issues ONE coalesced float4 load,
// 4 broadcast ds_reads of qs, 64 FMA.
// R5 post-mortem: the 4-deep kv rotation + explicit q double-buffer raised
// VGPR 76->96, dropped occupancy 27->19%, and LOST 15% despite the XCD
// swizzle collapsing FETCH 42->6 MB. So: R4's compiler-scheduled body
// (2-deep kv prefetch only; qs reads inline) + R5's swizzle, decoupled.
// __launch_bounds__(256,6) pins regalloc at <=85 VGPR (R4's body used 76).
// Per-(m,n) FMA chain is c-ascending -> bit-identical affinity values.
// Epilogue: 4 FULLY-UNROLLED rounds (rule #20: static acc indices only);
// each transposes one 4-m group through LDS; wave w emits m = mg0+4r+w with
// the ORIGINAL lane->n mapping -> theta grouping, candidate sets, counts,
// pair layout bit-identical to R1/R2/R4/R5. Merge kernel unchanged.
template <bool FULL>
__device__ __forceinline__ void emit_round(int r, int b, int seg, int mg0, int l, int w,
                                           uint64_t lmlt,
                                           uint32_t* __restrict__ cnt,
                                           uint2* __restrict__ pairs,
                                           float (&vv)[4][SEGN]) {
  const int m = mg0 + 4 * r + w;  // wave-uniform
  if (m < M) {
    // original lane->n mapping: vloc[idx] at n_local = 4l + 256*(idx>>2) + (idx&3)
    float vloc[16];
#pragma unroll
    for (int j = 0; j < 4; ++j) {
      const float4 q = *reinterpret_cast<const float4*>(&vv[w][4 * l + 256 * j]);
      vloc[4 * j + 0] = q.x;
      vloc[4 * j + 1] = q.y;
      vloc[4 * j + 2] = q.z;
      vloc[4 * j + 3] = q.w;
    }
    float a0 = fmaxf(fmaxf(vloc[0], vloc[1]), fmaxf(vloc[2], vloc[3]));
    float a1 = fmaxf(fmaxf(vloc[4], vloc[5]), fmaxf(vloc[6], vloc[7]));
    float a2 = fmaxf(fmaxf(vloc[8], vloc[9]), fmaxf(vloc[10], vloc[11]));
    float a3 = fmaxf(fmaxf(vloc[12], vloc[13]), fmaxf(vloc[14], vloc[15]));
    float s = fmaxf(fmaxf(a0, a1), fmaxf(a2, a3));
    // bitonic ascending sort of 64 lane maxima; lane 44 = 20th largest
#pragma unroll
    for (int kk = 2; kk <= 64; kk <<= 1) {
#pragma unroll
      for (int jj = kk >> 1; jj > 0; jj >>= 1) {
        const float o = __shfl_xor(s, jj, 64);
        const bool keepMin = (((l & kk) == 0) == ((l & jj) == 0));
        s = keepMin ? fminf(s, o) : fmaxf(s, o);
      }
    }
    const float th = __shfl(s, 44, 64);
    const size_t pbase = ((size_t)(b * M + m) * NSEG + seg) * CAP;
    int base = 0;
#pragma unroll
    for (int r16 = 0; r16 < 16; ++r16) {
      const bool hit = vloc[r16] >= th;
      const uint64_t mask = __ballot(hit);
      if (hit) {
        const int pos = base + (int)__popcll(mask & lmlt);
        if (pos < CAP)
          pairs[pbase + pos] = make_uint2(
              f2k(vloc[r16]),
              (uint32_t)(seg * SEGN + 4 * l + 256 * (r16 >> 2) + (r16 & 3)));
      }
      base += (int)__popcll(mask);
    }
    if (l == 0)
      cnt[(size_t)(b * M + m) * NSEG + seg] = (uint32_t)(base < CAP ? base : CAP);
  }
}

template <bool FULL>
__device__ __forceinline__ void fused_body(const float* __restrict__ mk,
                                           const float* __restrict__ qk,
                                           const float* __restrict__ asq,
                                           uint32_t* __restrict__ cnt,
                                           uint2* __restrict__ pairs,
                                           int b, int seg, int mg0,
                                           float (&qs)[CK][20],
                                           float (&vv)[4][SEGN]) {
  const int t = threadIdx.x;
  const int l = t & 63, w = t >> 6;

  for (int i = t; i < CK * 16; i += 256) {
    int c = i >> 4, ml = i & 15;
    int m = mg0 + ml;
    qs[c][ml] = (m < M) ? qk[((size_t)b * CK + c) * M + m] : 0.f;
  }
  __syncthreads();

  const int nl0 = w * 256 + 4 * l;      // n_local of this thread's float4
  const int nb  = seg * SEGN + nl0;     // global n
  const bool vld = FULL || (nb < N);    // N%4==0 -> whole float4 valid or not

  const float* p = mk + (size_t)b * CK * N + nb;

  float4 acc[16];
#pragma unroll
  for (int m = 0; m < 16; ++m) acc[m] = make_float4(0.f, 0.f, 0.f, 0.f);

  auto ld = [&](const float* q) -> float4 {
    return vld ? *reinterpret_cast<const float4*>(q) : make_float4(0.f, 0.f, 0.f, 0.f);
  };
  auto fmastep = [&](const float4& kv, int c) {
    const float4 q0 = *reinterpret_cast<const float4*>(&qs[c][0]);
    const float4 q1 = *reinterpret_cast<const float4*>(&qs[c][4]);
    const float4 q2 = *reinterpret_cast<const float4*>(&qs[c][8]);
    const float4 q3 = *reinterpret_cast<const float4*>(&qs[c][12]);
    const float qm[16] = {q0.x, q0.y, q0.z, q0.w, q1.x, q1.y, q1.z, q1.w,
                          q2.x, q2.y, q2.z, q2.w, q3.x, q3.y, q3.z, q3.w};
#pragma unroll
    for (int m = 0; m < 16; ++m) {
      acc[m].x += kv.x * qm[m];
      acc[m].y += kv.y * qm[m];
      acc[m].z += kv.z * qm[m];
      acc[m].w += kv.w * qm[m];
    }
  };

  // 2-deep rotating prefetch: load for c+2 issued while computing c
  float4 kva = ld(p);
  float4 kvb = ld(p + N);
  const float* pn = p + 2 * (size_t)N;
#pragma unroll 2
  for (int c = 0; c < CK - 2; ++c) {
    const float4 kvn = ld(pn);
    pn += N;
    fmastep(kva, c);
    kva = kvb;
    kvb = kvn;
  }
  fmastep(kva, CK - 2);
  fmastep(kvb, CK - 1);

  float4 sq4 = make_float4(0.f, 0.f, 0.f, 0.f);
  if (vld) sq4 = *reinterpret_cast<const float4*>(asq + (size_t)b * N + nb);

  const uint64_t lmlt = (1ull << l) - 1ull;

  // 4 epilogue rounds, fully unrolled: all acc indices compile-time constant.
#pragma unroll
  for (int r = 0; r < 4; ++r) {
#pragma unroll
    for (int mj = 0; mj < 4; ++mj) {
      const float4 a = acc[4 * r + mj];  // static: r, mj both unrolled
      float4 vr;
      vr.x = (2.f * a.x - sq4.x) * 0.125f;
      vr.y = (2.f * a.y - sq4.y) * 0.125f;
      vr.z = (2.f * a.z - sq4.z) * 0.125f;
      vr.w = (2.f * a.w - sq4.w) * 0.125f;
      if (!FULL && !vld) vr = make_float4(-FLT_MAX, -FLT_MAX, -FLT_MAX, -FLT_MAX);
      *reinterpret_cast<float4*>(&vv[mj][nl0]) = vr;
    }
    __syncthreads();
    emit_round<FULL>(r, b, seg, mg0, l, w, lmlt, cnt, pairs, vv);
    __syncthreads();
  }
}

// 1-D grid + bijective XCD swizzle (m204 formula): each XCD gets a contiguous
// wgid chunk; wgid orders mg fastest within (b,seg) -> all 102 blocks sharing
// one mk slice land on 1-2 XCDs -> kv loads are local-L2 hits (R5: FETCH
// 42 MB -> 6.0 MB, confirmed).
__global__ __launch_bounds__(256, 6) void fused_kernel(const float* __restrict__ mk,
                                                       const float* __restrict__ qk,
                                                       const float* __restrict__ asq,
                                                       uint32_t* __restrict__ cnt,
                                                       uint2* __restrict__ pairs) {
  __shared__ float qs[CK][20];   // 16 m padded to 20 (80B rows, 16B aligned)
  __shared__ float vv[4][SEGN];  // epilogue transpose buffer (16 KB)

  constexpr int NWG = NSEG * MG * B;  // 2652
  constexpr int NX = 8;
  constexpr int Q = NWG / NX, R = NWG % NX;  // 331, 4
  const int orig = blockIdx.x;
  const int xcd = orig & (NX - 1), idx = orig >> 3;
  const int wgid = (xcd < R ? xcd * (Q + 1) : R * (Q + 1) + (xcd - R) * Q) + idx;
  const int segb = wgid / MG;          // 0..B*NSEG-1 (b-major)
  const int mg   = wgid - segb * MG;
  const int b    = segb / NSEG;
  const int seg  = segb - b * NSEG;

  if (seg != NSEG - 1)
    fused_body<true>(mk, qk, asq, cnt, pairs, b, seg, mg * 16, qs, vv);
  else
    fused_body<false>(mk, qk, asq, cnt, pairs, b, seg, mg * 16, qs, vv);
}

// K3: merge candidates -> exact global top-20 (4-pass radix select, min-index
// tie-break) + softmax + fused gather into outT[b][m][c].
__global__ __launch_bounds__(256) void merge_topk_gather(const uint32_t* __restrict__ cnt,
                                                         const uint2* __restrict__ pairs,
                                                         const float* __restrict__ mvT,
                                                         float* __restrict__ outT) {
  const int m = blockIdx.x, b = blockIdx.y;
  const int t = threadIdx.x;

  __shared__ uint32_t segc[NSEG];
  constexpr int HP = 268;  // 1072B rows: 16B-aligned, non-pow2 bank offset
  __shared__ int hist[4][4][HP];
  __shared__ int s_digit, s_before;
  __shared__ int wn[K];
  __shared__ uint32_t wk[K];
  __shared__ float sw[K];
  __shared__ int gcnt, ecnt, s_last;
  __shared__ int ebuf[K];
  __shared__ int rmin4[4];

  if (t < NSEG) segc[t] = cnt[(size_t)(b * M + m) * NSEG + t];
  __syncthreads();

  const uint2* pb = pairs + (size_t)(b * M + m) * SLOTS;
  uint32_t k[JC];
  uint32_t nn[JC];
#pragma unroll
  for (int j = 0; j < JC; ++j) {
    int idx = t + (j << 8);
    bool valid = (idx < SLOTS) && ((uint32_t)(idx & (CAP - 1)) < segc[idx >> 6]);
    if (valid) {
      uint2 pr = pb[idx];
      k[j] = pr.x;
      nn[j] = pr.y;
    } else {
      k[j] = 0u;
      nn[j] = 0u;
    }
  }

  int before = 0;
  uint32_t pref = 0;
  const int w = t >> 6;
  const int rp = (t >> 4) & 3;
  int* myhist = &hist[w][rp][0];

  for (int p = 0; p < 4; ++p) {
    const int s = 24 - 8 * p;
    for (int i = t; i < 16 * HP; i += 256) ((int*)hist)[i] = 0;
    __syncthreads();
    const int shHi = (p == 0) ? 0 : (s + 8);
#pragma unroll
    for (int j = 0; j < JC; ++j) {
      uint32_t key = k[j];
      bool act = (p == 0) || ((key >> shHi) == pref);
      if (act) atomicAdd(&myhist[(key >> s) & 255], 1);
    }
    __syncthreads();
    if (t < 64) {
      int d = 4 * t;
      int4 g = make_int4(0, 0, 0, 0);
#pragma unroll
      for (int ww = 0; ww < 4; ++ww)
#pragma unroll
        for (int rr = 0; rr < 4; ++rr) {
          int4 h = *reinterpret_cast<int4*>(&hist[ww][rr][d]);
          g.x += h.x; g.y += h.y; g.z += h.z; g.w += h.w;
        }
      int sl = g.x + g.y + g.z + g.w;
      int sfx = sl;
#pragma unroll
      for (int off = 1; off < 64; off <<= 1) {
        int o = __shfl_down(sfx, off);
        sfx += (t + off < 64) ? o : 0;
      }
      int above = sfx - sl;
      int rem = K - before;
      if (above < rem && rem <= sfx) {  // boundary digit in my 4-digit group
        int cum = above, ds;
        if (cum + g.w >= rem) ds = 3;
        else { cum += g.w;
          if (cum + g.z >= rem) ds = 2;
          else { cum += g.z;
            if (cum + g.y >= rem) ds = 1;
            else { cum += g.y; ds = 0; } } }
        s_digit = 4 * t + ds;
        s_before = before + cum;
      }
    }
    __syncthreads();
    pref = (pref << 8) | (uint32_t)s_digit;
    before = s_before;
  }

  const uint32_t thr = pref;
  const int need = K - before;
  if (t == 0) { gcnt = 0; ecnt = 0; }
  __syncthreads();
#pragma unroll
  for (int j = 0; j < JC; ++j) {
    uint32_t key = k[j];
    if (key > thr) {
      int q = atomicAdd(&gcnt, 1);
      wn[q] = (int)nn[j]; wk[q] = key;
    } else if (key == thr) {
      int q = atomicAdd(&ecnt, 1);
      if (q < K) ebuf[q] = (int)nn[j];
    }
  }
  __syncthreads();
  if (ecnt == need) {
    if (t < need) { wn[before + t] = ebuf[t]; wk[before + t] = thr; }
  } else {
    // rare boundary tie: pick `need` smallest indices among key == thr
    int last = -1;
    for (int r = 0; r < need; ++r) {
      int loc = INT_MAX;
#pragma unroll
      for (int j = 0; j < JC; ++j) {
        int n = (int)nn[j];
        if (k[j] == thr && n > last && n < loc) loc = n;
      }
#pragma unroll
      for (int off = 1; off < 64; off <<= 1) loc = min(loc, __shfl_xor(loc, off));
      if ((t & 63) == 0) rmin4[t >> 6] = loc;
      __syncthreads();
      if (t == 0) {
        int mn = min(min(rmin4[0], rmin4[1]), min(rmin4[2], rmin4[3]));
        wn[before + r] = mn; wk[before + r] = thr; s_last = mn;
      }
      __syncthreads();
      last = s_last;
    }
  }
  __syncthreads();

  // softmax over the K winners (wave 0)
  if (t < 64) {
    float v = (t < K) ? k2f(wk[t]) : -FLT_MAX;
    float mx = v;
#pragma unroll
    for (int off = 1; off < 64; off <<= 1) mx = fmaxf(mx, __shfl_xor(mx, off));
    float e = (t < K) ? expf(v - mx) : 0.f;
    float ss = e;
#pragma unroll
    for (int off = 1; off < 64; off <<= 1) ss += __shfl_xor(ss, off);
    if (t < K) sw[t] = e / ss;
  }
  __syncthreads();

  // fused gather: outT[b][m][c] = sum_j sw[j] * mvT[b][wn[j]][c]  (float4 rows)
  if (t < CV / 4) {
    const float4* tb4 = reinterpret_cast<const float4*>(mvT + (size_t)b * N * CV);
    float4 s4 = make_float4(0.f, 0.f, 0.f, 0.f);
#pragma unroll
    for (int j = 0; j < K; ++j) {
      float wj = sw[j];
      float4 vv4 = tb4[(size_t)wn[j] * (CV / 4) + t];
      s4.x += wj * vv4.x; s4.y += wj * vv4.y; s4.z += wj * vv4.z; s4.w += wj * vv4.w;
    }
    reinterpret_cast<float4*>(outT + ((size_t)b * M + m) * CV)[t] = s4;
  }
}

}  // namespace

extern "C" void kernel_launch(void* const* d_in, const int* in_sizes, int n_in,
                              void* d_out, int out_size, void* d_ws, size_t ws_size,
                              hipStream_t stream) {
  const float* mk = (const float*)d_in[0];
  const float* qk = (const float*)d_in[1];
  const float* mv = (const float*)d_in[2];
  float* out = (float*)d_out;

  char* w = (char*)d_ws;
  float* asq = (float*)w;
  size_t o = (size_t)B * N * sizeof(float);                 // 103,680 B
  float* mvT = (float*)(w + o);
  o += (size_t)B * N * CV * sizeof(float);                  // +39,813,120 B
  float* outT = (float*)(w + o);
  o += (size_t)B * M * CV * sizeof(float);                  // +4,976,640 B
  uint32_t* cnt = (uint32_t*)(w + o);
  o += (size_t)B * M * NSEG * sizeof(uint32_t);             // +168,480 B
  uint2* pairs = (uint2*)(w + o);
  o += (size_t)B * M * NSEG * CAP * sizeof(uint2);          // +21,565,440 B  (total ~66.6 MB)

  transpose_kernel<<<dim3((N + 63) / 64, CV / 64, B), 256, 0, stream>>>(mv, mvT);
  asq_kernel<<<(B * N + 255) / 256, 256, 0, stream>>>(mk, asq);
  // cnt needs no memset: every (b, m<M, seg) is written by its owning wave.
  fused_kernel<<<dim3(NSEG * MG * B), 256, 0, stream>>>(mk, qk, asq, cnt, pairs);
  merge_topk_gather<<<dim3(M, B), 256, 0, stream>>>(cnt, pairs, mvT, outT);
  transpose_out_kernel<<<dim3((M + 63) / 64, CV / 64, B), 256, 0, stream>>>(outT, out);
}

// Round 7
// 241.199 us; speedup vs baseline: 2.6427x; 2.6427x over previous
//
#include <hip/hip_runtime.h>
#include <math.h>
#include <float.h>
#include <limits.h>
#include <stdint.h>

namespace {

constexpr int B  = 2;
constexpr int CK = 64;
constexpr int N  = 12960;   // T*H*W = 8*30*54
constexpr int M  = 1620;    // H*W = 30*54
constexpr int CV = 384;
constexpr int K  = 20;      // topk (setup fixed)

// segmented fused top-k geometry
constexpr int SEGN  = 1024;                    // n covered per stage-1 block
constexpr int NSEG  = (N + SEGN - 1) / SEGN;   // 13 segments
constexpr int CAP   = 64;                      // candidate slots per (m, seg); mean ~24, +8 sigma safe
constexpr int SLOTS = NSEG * CAP;              // 832 slots per (b, m)
constexpr int JC    = (SLOTS + 255) / 256;     // 4 candidate slots per thread in merge
constexpr int MG    = (M + 15) / 16;           // 102 m-groups

static_assert((CAP & (CAP - 1)) == 0, "CAP must be pow2 (slot>>6 indexing)");
static_assert(NSEG * SEGN >= N, "segments must cover N");

// monotone float->uint key (order-preserving) and inverse
__device__ __forceinline__ uint32_t f2k(float x) {
  uint32_t u = __float_as_uint(x);
  return u ^ ((u & 0x80000000u) ? 0xFFFFFFFFu : 0x80000000u);
}
__device__ __forceinline__ float k2f(uint32_t k) {
  uint32_t u = (k & 0x80000000u) ? (k ^ 0x80000000u) : ~k;
  return __uint_as_float(u);
}

// K0: mvT[b][n][c] = mv[b][c][n]  (so gather reads are contiguous in c)
__global__ __launch_bounds__(256) void transpose_kernel(const float* __restrict__ mv,
                                                        float* __restrict__ mvT) {
  __shared__ float tile[64][65];
  int b = blockIdx.z;
  int n0 = blockIdx.x * 64;
  int c0 = blockIdx.y * 64;
  int tx = threadIdx.x & 63, ty = threadIdx.x >> 6;
  for (int r = ty; r < 64; r += 4) {
    int c = c0 + r, n = n0 + tx;
    tile[r][tx] = (n < N) ? mv[((size_t)b * CV + c) * N + n] : 0.f;
  }
  __syncthreads();
  for (int r = ty; r < 64; r += 4) {
    int n = n0 + r, c = c0 + tx;
    if (n < N) mvT[((size_t)b * N + n) * CV + c] = tile[tx][r];
  }
}

// K5: out[b][c][m] = outT[b][m][c]
__global__ __launch_bounds__(256) void transpose_out_kernel(const float* __restrict__ outT,
                                                            float* __restrict__ out) {
  __shared__ float tile[64][65];
  int b = blockIdx.z;
  int m0 = blockIdx.x * 64;
  int c0 = blockIdx.y * 64;
  int tx = threadIdx.x & 63, ty = threadIdx.x >> 6;
  for (int r = ty; r < 64; r += 4) {
    int m = m0 + r;
    if (m < M) tile[r][tx] = outT[((size_t)b * M + m) * CV + c0 + tx];
  }
  __syncthreads();
  for (int r = ty; r < 64; r += 4) {
    int c = c0 + r, m = m0 + tx;
    if (m < M) out[((size_t)b * CV + c) * M + m] = tile[tx][r];
  }
}

// K1: a_sq[b,n] = sum_c mk[b,c,n]^2
__global__ __launch_bounds__(256) void asq_kernel(const float* __restrict__ mk,
                                                  float* __restrict__ asq) {
  int i = blockIdx.x * 256 + threadIdx.x;
  if (i >= B * N) return;
  int b = i / N, n = i - b * N;
  const float* p = mk + (size_t)b * CK * N + n;
  float s = 0.f;
#pragma unroll
  for (int c = 0; c < CK; ++c) {
    float v = p[(size_t)c * N];
    s += v * v;
  }
  asq[i] = s;
}

// K2 (fused, wave-per-chunk): block = 16 m x 1024 n. Wave w owns n-chunk w
// (256 n) for ALL 16 m -> per c each thread issues ONE coalesced float4 load,
// 4 broadcast ds_reads of qs, 64 FMA. 2-deep rotating kv prefetch; q reads
// left to the compiler (R5 showed hand-pipelining them costs occupancy).
// NO occupancy pin: R6's __launch_bounds__(256,6) squeezed regalloc to 40
// VGPR and spilled the accumulators (WRITE 9.5->719 MB, 552 us). R4's body
// naturally allocates 76 VGPR / ~27% occupancy — leave it alone.
// XCD swizzle (R5, kept): contiguous wgid chunk per XCD, mg fastest ->
// all 102 blocks sharing one (b,seg) mk slice on 1-2 XCDs -> kv L2-local
// (FETCH 42->6 MB, verified R5).
// Per-(m,n) FMA chain is c-ascending -> bit-identical affinity values.
// Epilogue: 4 FULLY-UNROLLED rounds (rule #20: static acc indices only);
// each transposes one 4-m group through LDS; wave w emits m = mg0+4r+w with
// the ORIGINAL lane->n mapping -> theta grouping, candidate sets, counts,
// pair layout bit-identical to R1/R2/R4/R5. Merge kernel unchanged.
template <bool FULL>
__device__ __forceinline__ void emit_round(int r, int b, int seg, int mg0, int l, int w,
                                           uint64_t lmlt,
                                           uint32_t* __restrict__ cnt,
                                           uint2* __restrict__ pairs,
                                           float (&vv)[4][SEGN]) {
  const int m = mg0 + 4 * r + w;  // wave-uniform
  if (m < M) {
    // original lane->n mapping: vloc[idx] at n_local = 4l + 256*(idx>>2) + (idx&3)
    float vloc[16];
#pragma unroll
    for (int j = 0; j < 4; ++j) {
      const float4 q = *reinterpret_cast<const float4*>(&vv[w][4 * l + 256 * j]);
      vloc[4 * j + 0] = q.x;
      vloc[4 * j + 1] = q.y;
      vloc[4 * j + 2] = q.z;
      vloc[4 * j + 3] = q.w;
    }
    float a0 = fmaxf(fmaxf(vloc[0], vloc[1]), fmaxf(vloc[2], vloc[3]));
    float a1 = fmaxf(fmaxf(vloc[4], vloc[5]), fmaxf(vloc[6], vloc[7]));
    float a2 = fmaxf(fmaxf(vloc[8], vloc[9]), fmaxf(vloc[10], vloc[11]));
    float a3 = fmaxf(fmaxf(vloc[12], vloc[13]), fmaxf(vloc[14], vloc[15]));
    float s = fmaxf(fmaxf(a0, a1), fmaxf(a2, a3));
    // bitonic ascending sort of 64 lane maxima; lane 44 = 20th largest
#pragma unroll
    for (int kk = 2; kk <= 64; kk <<= 1) {
#pragma unroll
      for (int jj = kk >> 1; jj > 0; jj >>= 1) {
        const float o = __shfl_xor(s, jj, 64);
        const bool keepMin = (((l & kk) == 0) == ((l & jj) == 0));
        s = keepMin ? fminf(s, o) : fmaxf(s, o);
      }
    }
    const float th = __shfl(s, 44, 64);
    const size_t pbase = ((size_t)(b * M + m) * NSEG + seg) * CAP;
    int base = 0;
#pragma unroll
    for (int r16 = 0; r16 < 16; ++r16) {
      const bool hit = vloc[r16] >= th;
      const uint64_t mask = __ballot(hit);
      if (hit) {
        const int pos = base + (int)__popcll(mask & lmlt);
        if (pos < CAP)
          pairs[pbase + pos] = make_uint2(
              f2k(vloc[r16]),
              (uint32_t)(seg * SEGN + 4 * l + 256 * (r16 >> 2) + (r16 & 3)));
      }
      base += (int)__popcll(mask);
    }
    if (l == 0)
      cnt[(size_t)(b * M + m) * NSEG + seg] = (uint32_t)(base < CAP ? base : CAP);
  }
}

template <bool FULL>
__device__ __forceinline__ void fused_body(const float* __restrict__ mk,
                                           const float* __restrict__ qk,
                                           const float* __restrict__ asq,
                                           uint32_t* __restrict__ cnt,
                                           uint2* __restrict__ pairs,
                                           int b, int seg, int mg0,
                                           float (&qs)[CK][20],
                                           float (&vv)[4][SEGN]) {
  const int t = threadIdx.x;
  const int l = t & 63, w = t >> 6;

  for (int i = t; i < CK * 16; i += 256) {
    int c = i >> 4, ml = i & 15;
    int m = mg0 + ml;
    qs[c][ml] = (m < M) ? qk[((size_t)b * CK + c) * M + m] : 0.f;
  }
  __syncthreads();

  const int nl0 = w * 256 + 4 * l;      // n_local of this thread's float4
  const int nb  = seg * SEGN + nl0;     // global n
  const bool vld = FULL || (nb < N);    // N%4==0 -> whole float4 valid or not

  const float* p = mk + (size_t)b * CK * N + nb;

  float4 acc[16];
#pragma unroll
  for (int m = 0; m < 16; ++m) acc[m] = make_float4(0.f, 0.f, 0.f, 0.f);

  auto ld = [&](const float* q) -> float4 {
    return vld ? *reinterpret_cast<const float4*>(q) : make_float4(0.f, 0.f, 0.f, 0.f);
  };
  auto fmastep = [&](const float4& kv, int c) {
    const float4 q0 = *reinterpret_cast<const float4*>(&qs[c][0]);
    const float4 q1 = *reinterpret_cast<const float4*>(&qs[c][4]);
    const float4 q2 = *reinterpret_cast<const float4*>(&qs[c][8]);
    const float4 q3 = *reinterpret_cast<const float4*>(&qs[c][12]);
    const float qm[16] = {q0.x, q0.y, q0.z, q0.w, q1.x, q1.y, q1.z, q1.w,
                          q2.x, q2.y, q2.z, q2.w, q3.x, q3.y, q3.z, q3.w};
#pragma unroll
    for (int m = 0; m < 16; ++m) {
      acc[m].x += kv.x * qm[m];
      acc[m].y += kv.y * qm[m];
      acc[m].z += kv.z * qm[m];
      acc[m].w += kv.w * qm[m];
    }
  };

  // 2-deep rotating prefetch: load for c+2 issued while computing c
  float4 kva = ld(p);
  float4 kvb = ld(p + N);
  const float* pn = p + 2 * (size_t)N;
#pragma unroll 2
  for (int c = 0; c < CK - 2; ++c) {
    const float4 kvn = ld(pn);
    pn += N;
    fmastep(kva, c);
    kva = kvb;
    kvb = kvn;
  }
  fmastep(kva, CK - 2);
  fmastep(kvb, CK - 1);

  float4 sq4 = make_float4(0.f, 0.f, 0.f, 0.f);
  if (vld) sq4 = *reinterpret_cast<const float4*>(asq + (size_t)b * N + nb);

  const uint64_t lmlt = (1ull << l) - 1ull;

  // 4 epilogue rounds, fully unrolled: all acc indices compile-time constant.
#pragma unroll
  for (int r = 0; r < 4; ++r) {
#pragma unroll
    for (int mj = 0; mj < 4; ++mj) {
      const float4 a = acc[4 * r + mj];  // static: r, mj both unrolled
      float4 vr;
      vr.x = (2.f * a.x - sq4.x) * 0.125f;
      vr.y = (2.f * a.y - sq4.y) * 0.125f;
      vr.z = (2.f * a.z - sq4.z) * 0.125f;
      vr.w = (2.f * a.w - sq4.w) * 0.125f;
      if (!FULL && !vld) vr = make_float4(-FLT_MAX, -FLT_MAX, -FLT_MAX, -FLT_MAX);
      *reinterpret_cast<float4*>(&vv[mj][nl0]) = vr;
    }
    __syncthreads();
    emit_round<FULL>(r, b, seg, mg0, l, w, lmlt, cnt, pairs, vv);
    __syncthreads();
  }
}

// 1-D grid + bijective XCD swizzle (m204 formula): each XCD gets a contiguous
// wgid chunk; wgid orders mg fastest within (b,seg) -> all 102 blocks sharing
// one mk slice land on 1-2 XCDs -> kv loads are local-L2 hits (R5: FETCH
// 42 MB -> 6.0 MB, confirmed).
__global__ __launch_bounds__(256) void fused_kernel(const float* __restrict__ mk,
                                                    const float* __restrict__ qk,
                                                    const float* __restrict__ asq,
                                                    uint32_t* __restrict__ cnt,
                                                    uint2* __restrict__ pairs) {
  __shared__ float qs[CK][20];   // 16 m padded to 20 (80B rows, 16B aligned)
  __shared__ float vv[4][SEGN];  // epilogue transpose buffer (16 KB)

  constexpr int NWG = NSEG * MG * B;  // 2652
  constexpr int NX = 8;
  constexpr int Q = NWG / NX, R = NWG % NX;  // 331, 4
  const int orig = blockIdx.x;
  const int xcd = orig & (NX - 1), idx = orig >> 3;
  const int wgid = (xcd < R ? xcd * (Q + 1) : R * (Q + 1) + (xcd - R) * Q) + idx;
  const int segb = wgid / MG;          // 0..B*NSEG-1 (b-major)
  const int mg   = wgid - segb * MG;
  const int b    = segb / NSEG;
  const int seg  = segb - b * NSEG;

  if (seg != NSEG - 1)
    fused_body<true>(mk, qk, asq, cnt, pairs, b, seg, mg * 16, qs, vv);
  else
    fused_body<false>(mk, qk, asq, cnt, pairs, b, seg, mg * 16, qs, vv);
}

// K3: merge candidates -> exact global top-20 (4-pass radix select, min-index
// tie-break) + softmax + fused gather into outT[b][m][c].
__global__ __launch_bounds__(256) void merge_topk_gather(const uint32_t* __restrict__ cnt,
                                                         const uint2* __restrict__ pairs,
                                                         const float* __restrict__ mvT,
                                                         float* __restrict__ outT) {
  const int m = blockIdx.x, b = blockIdx.y;
  const int t = threadIdx.x;

  __shared__ uint32_t segc[NSEG];
  constexpr int HP = 268;  // 1072B rows: 16B-aligned, non-pow2 bank offset
  __shared__ int hist[4][4][HP];
  __shared__ int s_digit, s_before;
  __shared__ int wn[K];
  __shared__ uint32_t wk[K];
  __shared__ float sw[K];
  __shared__ int gcnt, ecnt, s_last;
  __shared__ int ebuf[K];
  __shared__ int rmin4[4];

  if (t < NSEG) segc[t] = cnt[(size_t)(b * M + m) * NSEG + t];
  __syncthreads();

  const uint2* pb = pairs + (size_t)(b * M + m) * SLOTS;
  uint32_t k[JC];
  uint32_t nn[JC];
#pragma unroll
  for (int j = 0; j < JC; ++j) {
    int idx = t + (j << 8);
    bool valid = (idx < SLOTS) && ((uint32_t)(idx & (CAP - 1)) < segc[idx >> 6]);
    if (valid) {
      uint2 pr = pb[idx];
      k[j] = pr.x;
      nn[j] = pr.y;
    } else {
      k[j] = 0u;
      nn[j] = 0u;
    }
  }

  int before = 0;
  uint32_t pref = 0;
  const int w = t >> 6;
  const int rp = (t >> 4) & 3;
  int* myhist = &hist[w][rp][0];

  for (int p = 0; p < 4; ++p) {
    const int s = 24 - 8 * p;
    for (int i = t; i < 16 * HP; i += 256) ((int*)hist)[i] = 0;
    __syncthreads();
    const int shHi = (p == 0) ? 0 : (s + 8);
#pragma unroll
    for (int j = 0; j < JC; ++j) {
      uint32_t key = k[j];
      bool act = (p == 0) || ((key >> shHi) == pref);
      if (act) atomicAdd(&myhist[(key >> s) & 255], 1);
    }
    __syncthreads();
    if (t < 64) {
      int d = 4 * t;
      int4 g = make_int4(0, 0, 0, 0);
#pragma unroll
      for (int ww = 0; ww < 4; ++ww)
#pragma unroll
        for (int rr = 0; rr < 4; ++rr) {
          int4 h = *reinterpret_cast<int4*>(&hist[ww][rr][d]);
          g.x += h.x; g.y += h.y; g.z += h.z; g.w += h.w;
        }
      int sl = g.x + g.y + g.z + g.w;
      int sfx = sl;
#pragma unroll
      for (int off = 1; off < 64; off <<= 1) {
        int o = __shfl_down(sfx, off);
        sfx += (t + off < 64) ? o : 0;
      }
      int above = sfx - sl;
      int rem = K - before;
      if (above < rem && rem <= sfx) {  // boundary digit in my 4-digit group
        int cum = above, ds;
        if (cum + g.w >= rem) ds = 3;
        else { cum += g.w;
          if (cum + g.z >= rem) ds = 2;
          else { cum += g.z;
            if (cum + g.y >= rem) ds = 1;
            else { cum += g.y; ds = 0; } } }
        s_digit = 4 * t + ds;
        s_before = before + cum;
      }
    }
    __syncthreads();
    pref = (pref << 8) | (uint32_t)s_digit;
    before = s_before;
  }

  const uint32_t thr = pref;
  const int need = K - before;
  if (t == 0) { gcnt = 0; ecnt = 0; }
  __syncthreads();
#pragma unroll
  for (int j = 0; j < JC; ++j) {
    uint32_t key = k[j];
    if (key > thr) {
      int q = atomicAdd(&gcnt, 1);
      wn[q] = (int)nn[j]; wk[q] = key;
    } else if (key == thr) {
      int q = atomicAdd(&ecnt, 1);
      if (q < K) ebuf[q] = (int)nn[j];
    }
  }
  __syncthreads();
  if (ecnt == need) {
    if (t < need) { wn[before + t] = ebuf[t]; wk[before + t] = thr; }
  } else {
    // rare boundary tie: pick `need` smallest indices among key == thr
    int last = -1;
    for (int r = 0; r < need; ++r) {
      int loc = INT_MAX;
#pragma unroll
      for (int j = 0; j < JC; ++j) {
        int n = (int)nn[j];
        if (k[j] == thr && n > last && n < loc) loc = n;
      }
#pragma unroll
      for (int off = 1; off < 64; off <<= 1) loc = min(loc, __shfl_xor(loc, off));
      if ((t & 63) == 0) rmin4[t >> 6] = loc;
      __syncthreads();
      if (t == 0) {
        int mn = min(min(rmin4[0], rmin4[1]), min(rmin4[2], rmin4[3]));
        wn[before + r] = mn; wk[before + r] = thr; s_last = mn;
      }
      __syncthreads();
      last = s_last;
    }
  }
  __syncthreads();

  // softmax over the K winners (wave 0)
  if (t < 64) {
    float v = (t < K) ? k2f(wk[t]) : -FLT_MAX;
    float mx = v;
#pragma unroll
    for (int off = 1; off < 64; off <<= 1) mx = fmaxf(mx, __shfl_xor(mx, off));
    float e = (t < K) ? expf(v - mx) : 0.f;
    float ss = e;
#pragma unroll
    for (int off = 1; off < 64; off <<= 1) ss += __shfl_xor(ss, off);
    if (t < K) sw[t] = e / ss;
  }
  __syncthreads();

  // fused gather: outT[b][m][c] = sum_j sw[j] * mvT[b][wn[j]][c]  (float4 rows)
  if (t < CV / 4) {
    const float4* tb4 = reinterpret_cast<const float4*>(mvT + (size_t)b * N * CV);
    float4 s4 = make_float4(0.f, 0.f, 0.f, 0.f);
#pragma unroll
    for (int j = 0; j < K; ++j) {
      float wj = sw[j];
      float4 vv4 = tb4[(size_t)wn[j] * (CV / 4) + t];
      s4.x += wj * vv4.x; s4.y += wj * vv4.y; s4.z += wj * vv4.z; s4.w += wj * vv4.w;
    }
    reinterpret_cast<float4*>(outT + ((size_t)b * M + m) * CV)[t] = s4;
  }
}

}  // namespace

extern "C" void kernel_launch(void* const* d_in, const int* in_sizes, int n_in,
                              void* d_out, int out_size, void* d_ws, size_t ws_size,
                              hipStream_t stream) {
  const float* mk = (const float*)d_in[0];
  const float* qk = (const float*)d_in[1];
  const float* mv = (const float*)d_in[2];
  float* out = (float*)d_out;

  char* w = (char*)d_ws;
  float* asq = (float*)w;
  size_t o = (size_t)B * N * sizeof(float);                 // 103,680 B
  float* mvT = (float*)(w + o);
  o += (size_t)B * N * CV * sizeof(float);                  // +39,813,120 B
  float* outT = (float*)(w + o);
  o += (size_t)B * M * CV * sizeof(float);                  // +4,976,640 B
  uint32_t* cnt = (uint32_t*)(w + o);
  o += (size_t)B * M * NSEG * sizeof(uint32_t);             // +168,480 B
  uint2* pairs = (uint2*)(w + o);
  o += (size_t)B * M * NSEG * CAP * sizeof(uint2);          // +21,565,440 B  (total ~66.6 MB)

  transpose_kernel<<<dim3((N + 63) / 64, CV / 64, B), 256, 0, stream>>>(mv, mvT);
  asq_kernel<<<(B * N + 255) / 256, 256, 0, stream>>>(mk, asq);
  // cnt needs no memset: every (b, m<M, seg) is written by its owning wave.
  fused_kernel<<<dim3(NSEG * MG * B), 256, 0, stream>>>(mk, qk, asq, cnt, pairs);
  merge_topk_gather<<<dim3(M, B), 256, 0, stream>>>(cnt, pairs, mvT, outT);
  transpose_out_kernel<<<dim3((M + 63) / 64, CV / 64, B), 256, 0, stream>>>(outT, out);
}

// Round 8
// 231.326 us; speedup vs baseline: 2.7555x; 1.0427x over previous
//
#include <hip/hip_runtime.h>
#include <math.h>
#include <float.h>
#include <limits.h>
#include <stdint.h>

namespace {

constexpr int B  = 2;
constexpr int CK = 64;
constexpr int N  = 12960;   // T*H*W = 8*30*54
constexpr int M  = 1620;    // H*W = 30*54
constexpr int CV = 384;
constexpr int K  = 20;      // topk (setup fixed)

// segmented fused top-k geometry
constexpr int SEGN  = 1024;                    // n covered per stage-1 block
constexpr int NSEG  = (N + SEGN - 1) / SEGN;   // 13 segments
constexpr int CAP   = 64;                      // candidate slots per (m, seg); mean ~24, +8 sigma safe
constexpr int SLOTS = NSEG * CAP;              // 832 slots per (b, m)
constexpr int JC    = (SLOTS + 255) / 256;     // 4 candidate slots per thread in merge
constexpr int MG    = (M + 15) / 16;           // 102 m-groups
constexpr int MP    = MG * 16;                 // 1632: qk padded M (m-group always in range)

static_assert((CAP & (CAP - 1)) == 0, "CAP must be pow2 (slot>>6 indexing)");
static_assert(NSEG * SEGN >= N, "segments must cover N");

// monotone float->uint key (order-preserving) and inverse
__device__ __forceinline__ uint32_t f2k(float x) {
  uint32_t u = __float_as_uint(x);
  return u ^ ((u & 0x80000000u) ? 0xFFFFFFFFu : 0x80000000u);
}
__device__ __forceinline__ float k2f(uint32_t k) {
  uint32_t u = (k & 0x80000000u) ? (k ^ 0x80000000u) : ~k;
  return __uint_as_float(u);
}

// K0: mvT[b][n][c] = mv[b][c][n]  (so gather reads are contiguous in c)
__global__ __launch_bounds__(256) void transpose_kernel(const float* __restrict__ mv,
                                                        float* __restrict__ mvT) {
  __shared__ float tile[64][65];
  int b = blockIdx.z;
  int n0 = blockIdx.x * 64;
  int c0 = blockIdx.y * 64;
  int tx = threadIdx.x & 63, ty = threadIdx.x >> 6;
  for (int r = ty; r < 64; r += 4) {
    int c = c0 + r, n = n0 + tx;
    tile[r][tx] = (n < N) ? mv[((size_t)b * CV + c) * N + n] : 0.f;
  }
  __syncthreads();
  for (int r = ty; r < 64; r += 4) {
    int n = n0 + r, c = c0 + tx;
    if (n < N) mvT[((size_t)b * N + n) * CV + c] = tile[tx][r];
  }
}

// K5: out[b][c][m] = outT[b][m][c]
__global__ __launch_bounds__(256) void transpose_out_kernel(const float* __restrict__ outT,
                                                            float* __restrict__ out) {
  __shared__ float tile[64][65];
  int b = blockIdx.z;
  int m0 = blockIdx.x * 64;
  int c0 = blockIdx.y * 64;
  int tx = threadIdx.x & 63, ty = threadIdx.x >> 6;
  for (int r = ty; r < 64; r += 4) {
    int m = m0 + r;
    if (m < M) tile[r][tx] = outT[((size_t)b * M + m) * CV + c0 + tx];
  }
  __syncthreads();
  for (int r = ty; r < 64; r += 4) {
    int c = c0 + r, m = m0 + tx;
    if (m < M) out[((size_t)b * CV + c) * M + m] = tile[tx][r];
  }
}

// K1: a_sq[b,n] = sum_c mk[b,c,n]^2
__global__ __launch_bounds__(256) void asq_kernel(const float* __restrict__ mk,
                                                  float* __restrict__ asq) {
  int i = blockIdx.x * 256 + threadIdx.x;
  if (i >= B * N) return;
  int b = i / N, n = i - b * N;
  const float* p = mk + (size_t)b * CK * N + n;
  float s = 0.f;
#pragma unroll
  for (int c = 0; c < CK; ++c) {
    float v = p[(size_t)c * N];
    s += v * v;
  }
  asq[i] = s;
}

// K1b: qkp[b][c][MP] = qk[b][c][m] padded with 0 for m >= M (bit-identical to
// the old LDS-staging zero-fill; lets the fused kernel read q rows with NO
// bounds check and 64B-aligned uniform addresses -> s_load_dwordx16).
__global__ __launch_bounds__(256) void qkpad_kernel(const float* __restrict__ qk,
                                                    float* __restrict__ qkp) {
  int i = blockIdx.x * 256 + threadIdx.x;
  if (i >= B * CK * MP) return;
  int row = i / MP, mp = i - row * MP;
  qkp[i] = (mp < M) ? qk[(size_t)row * M + mp] : 0.f;
}

// K2 (fused, wave-per-chunk, SGPR-q): block = 16 m x 1024 n. Wave w owns
// n-chunk w (256 n) for ALL 16 m -> per c each thread issues ONE coalesced
// float4 kv load + 64 FMA whose q operand is a WAVE-UNIFORM scalar load
// (qkp row, uniform address -> s_load via scalar cache; v_fmac takes the
// SGPR operand directly). R7 null result proved kv locality is NOT the
// stall (FETCH 42->6 MB, dur unchanged); the exposed latency was the 4
// per-c ds_read_b128 of qs consumed immediately. This removes the LDS
// q-path entirely (staging loop, barrier, 5 KB LDS, all ds_reads).
// 2-deep rotating kv prefetch kept. Per-(m,n) FMA chain is c-ascending with
// identical q values -> bit-identical affinity.
// Epilogue: 4 FULLY-UNROLLED rounds (rule #20: static acc indices only);
// each transposes one 4-m group through LDS; wave w emits m = mg0+4r+w with
// the ORIGINAL lane->n mapping -> theta grouping, candidate sets, counts,
// pair layout bit-identical to R1-R7. Merge kernel unchanged.
template <bool FULL>
__device__ __forceinline__ void emit_round(int r, int b, int seg, int mg0, int l, int w,
                                           uint64_t lmlt,
                                           uint32_t* __restrict__ cnt,
                                           uint2* __restrict__ pairs,
                                           float (&vv)[4][SEGN]) {
  const int m = mg0 + 4 * r + w;  // wave-uniform
  if (m < M) {
    // original lane->n mapping: vloc[idx] at n_local = 4l + 256*(idx>>2) + (idx&3)
    float vloc[16];
#pragma unroll
    for (int j = 0; j < 4; ++j) {
      const float4 q = *reinterpret_cast<const float4*>(&vv[w][4 * l + 256 * j]);
      vloc[4 * j + 0] = q.x;
      vloc[4 * j + 1] = q.y;
      vloc[4 * j + 2] = q.z;
      vloc[4 * j + 3] = q.w;
    }
    float a0 = fmaxf(fmaxf(vloc[0], vloc[1]), fmaxf(vloc[2], vloc[3]));
    float a1 = fmaxf(fmaxf(vloc[4], vloc[5]), fmaxf(vloc[6], vloc[7]));
    float a2 = fmaxf(fmaxf(vloc[8], vloc[9]), fmaxf(vloc[10], vloc[11]));
    float a3 = fmaxf(fmaxf(vloc[12], vloc[13]), fmaxf(vloc[14], vloc[15]));
    float s = fmaxf(fmaxf(a0, a1), fmaxf(a2, a3));
    // bitonic ascending sort of 64 lane maxima; lane 44 = 20th largest
#pragma unroll
    for (int kk = 2; kk <= 64; kk <<= 1) {
#pragma unroll
      for (int jj = kk >> 1; jj > 0; jj >>= 1) {
        const float o = __shfl_xor(s, jj, 64);
        const bool keepMin = (((l & kk) == 0) == ((l & jj) == 0));
        s = keepMin ? fminf(s, o) : fmaxf(s, o);
      }
    }
    const float th = __shfl(s, 44, 64);
    const size_t pbase = ((size_t)(b * M + m) * NSEG + seg) * CAP;
    int base = 0;
#pragma unroll
    for (int r16 = 0; r16 < 16; ++r16) {
      const bool hit = vloc[r16] >= th;
      const uint64_t mask = __ballot(hit);
      if (hit) {
        const int pos = base + (int)__popcll(mask & lmlt);
        if (pos < CAP)
          pairs[pbase + pos] = make_uint2(
              f2k(vloc[r16]),
              (uint32_t)(seg * SEGN + 4 * l + 256 * (r16 >> 2) + (r16 & 3)));
      }
      base += (int)__popcll(mask);
    }
    if (l == 0)
      cnt[(size_t)(b * M + m) * NSEG + seg] = (uint32_t)(base < CAP ? base : CAP);
  }
}

template <bool FULL>
__device__ __forceinline__ void fused_body(const float* __restrict__ mk,
                                           const float* __restrict__ qkp,
                                           const float* __restrict__ asq,
                                           uint32_t* __restrict__ cnt,
                                           uint2* __restrict__ pairs,
                                           int b, int seg, int mg0,
                                           float (&vv)[4][SEGN]) {
  const int t = threadIdx.x;
  const int l = t & 63, w = t >> 6;

  const int nl0 = w * 256 + 4 * l;      // n_local of this thread's float4
  const int nb  = seg * SEGN + nl0;     // global n
  const bool vld = FULL || (nb < N);    // N%4==0 -> whole float4 valid or not

  const float* p = mk + (size_t)b * CK * N + nb;
  // wave-uniform q row base: 64B-aligned (MP and mg0 multiples of 16)
  const float* qrow = qkp + (size_t)b * CK * MP + mg0;

  float4 acc[16];
#pragma unroll
  for (int m = 0; m < 16; ++m) acc[m] = make_float4(0.f, 0.f, 0.f, 0.f);

  auto ld = [&](const float* q) -> float4 {
    return vld ? *reinterpret_cast<const float4*>(q) : make_float4(0.f, 0.f, 0.f, 0.f);
  };
  auto fmastep = [&](const float4& kv, const float* __restrict__ qc) {
#pragma unroll
    for (int m = 0; m < 16; ++m) {
      const float qm = qc[m];  // uniform address -> scalar load / SGPR operand
      acc[m].x += kv.x * qm;
      acc[m].y += kv.y * qm;
      acc[m].z += kv.z * qm;
      acc[m].w += kv.w * qm;
    }
  };

  // 2-deep rotating prefetch: load for c+2 issued while computing c
  float4 kva = ld(p);
  float4 kvb = ld(p + N);
  const float* pn = p + 2 * (size_t)N;
#pragma unroll 2
  for (int c = 0; c < CK - 2; ++c) {
    const float4 kvn = ld(pn);
    pn += N;
    fmastep(kva, qrow + (size_t)c * MP);
    kva = kvb;
    kvb = kvn;
  }
  fmastep(kva, qrow + (size_t)(CK - 2) * MP);
  fmastep(kvb, qrow + (size_t)(CK - 1) * MP);

  float4 sq4 = make_float4(0.f, 0.f, 0.f, 0.f);
  if (vld) sq4 = *reinterpret_cast<const float4*>(asq + (size_t)b * N + nb);

  const uint64_t lmlt = (1ull << l) - 1ull;

  // 4 epilogue rounds, fully unrolled: all acc indices compile-time constant.
#pragma unroll
  for (int r = 0; r < 4; ++r) {
#pragma unroll
    for (int mj = 0; mj < 4; ++mj) {
      const float4 a = acc[4 * r + mj];  // static: r, mj both unrolled
      float4 vr;
      vr.x = (2.f * a.x - sq4.x) * 0.125f;
      vr.y = (2.f * a.y - sq4.y) * 0.125f;
      vr.z = (2.f * a.z - sq4.z) * 0.125f;
      vr.w = (2.f * a.w - sq4.w) * 0.125f;
      if (!FULL && !vld) vr = make_float4(-FLT_MAX, -FLT_MAX, -FLT_MAX, -FLT_MAX);
      *reinterpret_cast<float4*>(&vv[mj][nl0]) = vr;
    }
    __syncthreads();
    emit_round<FULL>(r, b, seg, mg0, l, w, lmlt, cnt, pairs, vv);
    __syncthreads();
  }
}

// 1-D grid + bijective XCD swizzle (m204 formula): each XCD gets a contiguous
// wgid chunk; wgid orders mg fastest within (b,seg) -> all 102 blocks sharing
// one mk slice land on 1-2 XCDs -> kv loads are local-L2 hits (R5/R7: FETCH
// 42 MB -> 6.0 MB, confirmed).
__global__ __launch_bounds__(256) void fused_kernel(const float* __restrict__ mk,
                                                    const float* __restrict__ qkp,
                                                    const float* __restrict__ asq,
                                                    uint32_t* __restrict__ cnt,
                                                    uint2* __restrict__ pairs) {
  __shared__ float vv[4][SEGN];  // epilogue transpose buffer (16 KB; qs gone)

  constexpr int NWG = NSEG * MG * B;  // 2652
  constexpr int NX = 8;
  constexpr int Q = NWG / NX, R = NWG % NX;  // 331, 4
  const int orig = blockIdx.x;
  const int xcd = orig & (NX - 1), idx = orig >> 3;
  const int wgid = (xcd < R ? xcd * (Q + 1) : R * (Q + 1) + (xcd - R) * Q) + idx;
  const int segb = wgid / MG;          // 0..B*NSEG-1 (b-major)
  const int mg   = wgid - segb * MG;
  const int b    = segb / NSEG;
  const int seg  = segb - b * NSEG;

  if (seg != NSEG - 1)
    fused_body<true>(mk, qkp, asq, cnt, pairs, b, seg, mg * 16, vv);
  else
    fused_body<false>(mk, qkp, asq, cnt, pairs, b, seg, mg * 16, vv);
}

// K3: merge candidates -> exact global top-20 (4-pass radix select, min-index
// tie-break) + softmax + fused gather into outT[b][m][c].
__global__ __launch_bounds__(256) void merge_topk_gather(const uint32_t* __restrict__ cnt,
                                                         const uint2* __restrict__ pairs,
                                                         const float* __restrict__ mvT,
                                                         float* __restrict__ outT) {
  const int m = blockIdx.x, b = blockIdx.y;
  const int t = threadIdx.x;

  __shared__ uint32_t segc[NSEG];
  constexpr int HP = 268;  // 1072B rows: 16B-aligned, non-pow2 bank offset
  __shared__ int hist[4][4][HP];
  __shared__ int s_digit, s_before;
  __shared__ int wn[K];
  __shared__ uint32_t wk[K];
  __shared__ float sw[K];
  __shared__ int gcnt, ecnt, s_last;
  __shared__ int ebuf[K];
  __shared__ int rmin4[4];

  if (t < NSEG) segc[t] = cnt[(size_t)(b * M + m) * NSEG + t];
  __syncthreads();

  const uint2* pb = pairs + (size_t)(b * M + m) * SLOTS;
  uint32_t k[JC];
  uint32_t nn[JC];
#pragma unroll
  for (int j = 0; j < JC; ++j) {
    int idx = t + (j << 8);
    bool valid = (idx < SLOTS) && ((uint32_t)(idx & (CAP - 1)) < segc[idx >> 6]);
    if (valid) {
      uint2 pr = pb[idx];
      k[j] = pr.x;
      nn[j] = pr.y;
    } else {
      k[j] = 0u;
      nn[j] = 0u;
    }
  }

  int before = 0;
  uint32_t pref = 0;
  const int w = t >> 6;
  const int rp = (t >> 4) & 3;
  int* myhist = &hist[w][rp][0];

  for (int p = 0; p < 4; ++p) {
    const int s = 24 - 8 * p;
    for (int i = t; i < 16 * HP; i += 256) ((int*)hist)[i] = 0;
    __syncthreads();
    const int shHi = (p == 0) ? 0 : (s + 8);
#pragma unroll
    for (int j = 0; j < JC; ++j) {
      uint32_t key = k[j];
      bool act = (p == 0) || ((key >> shHi) == pref);
      if (act) atomicAdd(&myhist[(key >> s) & 255], 1);
    }
    __syncthreads();
    if (t < 64) {
      int d = 4 * t;
      int4 g = make_int4(0, 0, 0, 0);
#pragma unroll
      for (int ww = 0; ww < 4; ++ww)
#pragma unroll
        for (int rr = 0; rr < 4; ++rr) {
          int4 h = *reinterpret_cast<int4*>(&hist[ww][rr][d]);
          g.x += h.x; g.y += h.y; g.z += h.z; g.w += h.w;
        }
      int sl = g.x + g.y + g.z + g.w;
      int sfx = sl;
#pragma unroll
      for (int off = 1; off < 64; off <<= 1) {
        int o = __shfl_down(sfx, off);
        sfx += (t + off < 64) ? o : 0;
      }
      int above = sfx - sl;
      int rem = K - before;
      if (above < rem && rem <= sfx) {  // boundary digit in my 4-digit group
        int cum = above, ds;
        if (cum + g.w >= rem) ds = 3;
        else { cum += g.w;
          if (cum + g.z >= rem) ds = 2;
          else { cum += g.z;
            if (cum + g.y >= rem) ds = 1;
            else { cum += g.y; ds = 0; } } }
        s_digit = 4 * t + ds;
        s_before = before + cum;
      }
    }
    __syncthreads();
    pref = (pref << 8) | (uint32_t)s_digit;
    before = s_before;
  }

  const uint32_t thr = pref;
  const int need = K - before;
  if (t == 0) { gcnt = 0; ecnt = 0; }
  __syncthreads();
#pragma unroll
  for (int j = 0; j < JC; ++j) {
    uint32_t key = k[j];
    if (key > thr) {
      int q = atomicAdd(&gcnt, 1);
      wn[q] = (int)nn[j]; wk[q] = key;
    } else if (key == thr) {
      int q = atomicAdd(&ecnt, 1);
      if (q < K) ebuf[q] = (int)nn[j];
    }
  }
  __syncthreads();
  if (ecnt == need) {
    if (t < need) { wn[before + t] = ebuf[t]; wk[before + t] = thr; }
  } else {
    // rare boundary tie: pick `need` smallest indices among key == thr
    int last = -1;
    for (int r = 0; r < need; ++r) {
      int loc = INT_MAX;
#pragma unroll
      for (int j = 0; j < JC; ++j) {
        int n = (int)nn[j];
        if (k[j] == thr && n > last && n < loc) loc = n;
      }
#pragma unroll
      for (int off = 1; off < 64; off <<= 1) loc = min(loc, __shfl_xor(loc, off));
      if ((t & 63) == 0) rmin4[t >> 6] = loc;
      __syncthreads();
      if (t == 0) {
        int mn = min(min(rmin4[0], rmin4[1]), min(rmin4[2], rmin4[3]));
        wn[before + r] = mn; wk[before + r] = thr; s_last = mn;
      }
      __syncthreads();
      last = s_last;
    }
  }
  __syncthreads();

  // softmax over the K winners (wave 0)
  if (t < 64) {
    float v = (t < K) ? k2f(wk[t]) : -FLT_MAX;
    float mx = v;
#pragma unroll
    for (int off = 1; off < 64; off <<= 1) mx = fmaxf(mx, __shfl_xor(mx, off));
    float e = (t < K) ? expf(v - mx) : 0.f;
    float ss = e;
#pragma unroll
    for (int off = 1; off < 64; off <<= 1) ss += __shfl_xor(ss, off);
    if (t < K) sw[t] = e / ss;
  }
  __syncthreads();

  // fused gather: outT[b][m][c] = sum_j sw[j] * mvT[b][wn[j]][c]  (float4 rows)
  if (t < CV / 4) {
    const float4* tb4 = reinterpret_cast<const float4*>(mvT + (size_t)b * N * CV);
    float4 s4 = make_float4(0.f, 0.f, 0.f, 0.f);
#pragma unroll
    for (int j = 0; j < K; ++j) {
      float wj = sw[j];
      float4 vv4 = tb4[(size_t)wn[j] * (CV / 4) + t];
      s4.x += wj * vv4.x; s4.y += wj * vv4.y; s4.z += wj * vv4.z; s4.w += wj * vv4.w;
    }
    reinterpret_cast<float4*>(outT + ((size_t)b * M + m) * CV)[t] = s4;
  }
}

}  // namespace

extern "C" void kernel_launch(void* const* d_in, const int* in_sizes, int n_in,
                              void* d_out, int out_size, void* d_ws, size_t ws_size,
                              hipStream_t stream) {
  const float* mk = (const float*)d_in[0];
  const float* qk = (const float*)d_in[1];
  const float* mv = (const float*)d_in[2];
  float* out = (float*)d_out;

  char* w = (char*)d_ws;
  float* asq = (float*)w;
  size_t o = (size_t)B * N * sizeof(float);                 // 103,680 B
  float* mvT = (float*)(w + o);
  o += (size_t)B * N * CV * sizeof(float);                  // +39,813,120 B
  float* outT = (float*)(w + o);
  o += (size_t)B * M * CV * sizeof(float);                  // +4,976,640 B
  uint32_t* cnt = (uint32_t*)(w + o);
  o += (size_t)B * M * NSEG * sizeof(uint32_t);             // +168,480 B
  uint2* pairs = (uint2*)(w + o);
  o += (size_t)B * M * NSEG * CAP * sizeof(uint2);          // +21,565,440 B
  float* qkp = (float*)(w + o);
  o += (size_t)B * CK * MP * sizeof(float);                 // +835,584 B (total ~67.5 MB)

  transpose_kernel<<<dim3((N + 63) / 64, CV / 64, B), 256, 0, stream>>>(mv, mvT);
  asq_kernel<<<(B * N + 255) / 256, 256, 0, stream>>>(mk, asq);
  qkpad_kernel<<<(B * CK * MP + 255) / 256, 256, 0, stream>>>(qk, qkp);
  // cnt needs no memset: every (b, m<M, seg) is written by its owning wave.
  fused_kernel<<<dim3(NSEG * MG * B), 256, 0, stream>>>(mk, qkp, asq, cnt, pairs);
  merge_topk_gather<<<dim3(M, B), 256, 0, stream>>>(cnt, pairs, mvT, outT);
  transpose_out_kernel<<<dim3((M + 63) / 64, CV / 64, B), 256, 0, stream>>>(outT, out);
}

// Round 9
// 220.758 us; speedup vs baseline: 2.8874x; 1.0479x over previous
//
#include <hip/hip_runtime.h>
#include <math.h>
#include <float.h>
#include <limits.h>
#include <stdint.h>

namespace {

constexpr int B  = 2;
constexpr int CK = 64;
constexpr int N  = 12960;   // T*H*W = 8*30*54
constexpr int M  = 1620;    // H*W = 30*54
constexpr int CV = 384;
constexpr int K  = 20;      // topk (setup fixed)

// segmented fused top-k geometry
constexpr int SEGN  = 1024;                    // n covered per stage-1 block
constexpr int NSEG  = (N + SEGN - 1) / SEGN;   // 13 segments
constexpr int CAP   = 64;                      // candidate slots per (m, seg); mean ~24, +8 sigma safe
constexpr int SLOTS = NSEG * CAP;              // 832 slots per (b, m)
constexpr int JC    = (SLOTS + 255) / 256;     // 4 candidate slots per thread in merge
constexpr int MG    = (M + 15) / 16;           // 102 m-groups
constexpr int MP    = MG * 16;                 // 1632: qk padded M

constexpr int NWG   = NSEG * MG * B;           // 2652 fused blocks
constexpr int TXB   = (N + 63) / 64;           // 203 transpose n-tiles
constexpr int TRB   = TXB * (CV / 64) * B;     // 2436 transpose blocks
constexpr int ASQB  = (B * N + 255) / 256;     // 102 asq blocks
constexpr int QKPB  = (B * CK * MP) / 256;     // 816 qkpad blocks (exact)

static_assert((CAP & (CAP - 1)) == 0, "CAP must be pow2");
static_assert(NSEG * SEGN >= N, "segments must cover N");
static_assert(B * CK * MP % 256 == 0, "qkpad grid exact");

// monotone float->uint key (order-preserving) and inverse
__device__ __forceinline__ uint32_t f2k(float x) {
  uint32_t u = __float_as_uint(x);
  return u ^ ((u & 0x80000000u) ? 0xFFFFFFFFu : 0x80000000u);
}
__device__ __forceinline__ float k2f(uint32_t k) {
  uint32_t u = (k & 0x80000000u) ? (k ^ 0x80000000u) : ~k;
  return __uint_as_float(u);
}

// K1 (prep): asq[b,n] = sum_c mk[b,c,n]^2  AND  qkp zero-padded copy of qk.
__global__ __launch_bounds__(256) void prep_kernel(const float* __restrict__ mk,
                                                   const float* __restrict__ qk,
                                                   float* __restrict__ asq,
                                                   float* __restrict__ qkp) {
  const int id = blockIdx.x, t = threadIdx.x;
  if (id < ASQB) {
    int i = id * 256 + t;
    if (i >= B * N) return;
    int b = i / N, n = i - b * N;
    const float* p = mk + (size_t)b * CK * N + n;
    float s = 0.f;
#pragma unroll
    for (int c = 0; c < CK; ++c) {
      float v = p[(size_t)c * N];
      s += v * v;
    }
    asq[i] = s;
  } else {
    int i = (id - ASQB) * 256 + t;   // < B*CK*MP exactly
    int row = i / MP, mp = i - row * MP;
    qkp[i] = (mp < M) ? qk[(size_t)row * M + mp] : 0.f;
  }
}

// K5: out[b][c][m] = outT[b][m][c]
__global__ __launch_bounds__(256) void transpose_out_kernel(const float* __restrict__ outT,
                                                            float* __restrict__ out) {
  __shared__ float tile[64][65];
  int b = blockIdx.z;
  int m0 = blockIdx.x * 64;
  int c0 = blockIdx.y * 64;
  int tx = threadIdx.x & 63, ty = threadIdx.x >> 6;
  for (int r = ty; r < 64; r += 4) {
    int m = m0 + r;
    if (m < M) tile[r][tx] = outT[((size_t)b * M + m) * CV + c0 + tx];
  }
  __syncthreads();
  for (int r = ty; r < 64; r += 4) {
    int c = c0 + r, m = m0 + tx;
    if (m < M) out[((size_t)b * CV + c) * M + m] = tile[tx][r];
  }
}

// K2 (fused, wave-per-chunk, SGPR-q) — body unchanged from R8 (verified best:
// 108 us, FETCH 7.6 MB, 0 bank conflicts). See R8 notes: kv 2-deep prefetch,
// q via wave-uniform scalar loads from padded qkp, epilogue 4 fully-unrolled
// LDS-transpose emit rounds, selection bit-identical to R1-R8.
template <bool FULL>
__device__ __forceinline__ void emit_round(int r, int b, int seg, int mg0, int l, int w,
                                           uint64_t lmlt,
                                           uint32_t* __restrict__ cnt,
                                           uint2* __restrict__ pairs,
                                           float (&vv)[4][SEGN]) {
  const int m = mg0 + 4 * r + w;  // wave-uniform
  if (m < M) {
    float vloc[16];
#pragma unroll
    for (int j = 0; j < 4; ++j) {
      const float4 q = *reinterpret_cast<const float4*>(&vv[w][4 * l + 256 * j]);
      vloc[4 * j + 0] = q.x;
      vloc[4 * j + 1] = q.y;
      vloc[4 * j + 2] = q.z;
      vloc[4 * j + 3] = q.w;
    }
    float a0 = fmaxf(fmaxf(vloc[0], vloc[1]), fmaxf(vloc[2], vloc[3]));
    float a1 = fmaxf(fmaxf(vloc[4], vloc[5]), fmaxf(vloc[6], vloc[7]));
    float a2 = fmaxf(fmaxf(vloc[8], vloc[9]), fmaxf(vloc[10], vloc[11]));
    float a3 = fmaxf(fmaxf(vloc[12], vloc[13]), fmaxf(vloc[14], vloc[15]));
    float s = fmaxf(fmaxf(a0, a1), fmaxf(a2, a3));
#pragma unroll
    for (int kk = 2; kk <= 64; kk <<= 1) {
#pragma unroll
      for (int jj = kk >> 1; jj > 0; jj >>= 1) {
        const float o = __shfl_xor(s, jj, 64);
        const bool keepMin = (((l & kk) == 0) == ((l & jj) == 0));
        s = keepMin ? fminf(s, o) : fmaxf(s, o);
      }
    }
    const float th = __shfl(s, 44, 64);
    const size_t pbase = ((size_t)(b * M + m) * NSEG + seg) * CAP;
    int base = 0;
#pragma unroll
    for (int r16 = 0; r16 < 16; ++r16) {
      const bool hit = vloc[r16] >= th;
      const uint64_t mask = __ballot(hit);
      if (hit) {
        const int pos = base + (int)__popcll(mask & lmlt);
        if (pos < CAP)
          pairs[pbase + pos] = make_uint2(
              f2k(vloc[r16]),
              (uint32_t)(seg * SEGN + 4 * l + 256 * (r16 >> 2) + (r16 & 3)));
      }
      base += (int)__popcll(mask);
    }
    if (l == 0)
      cnt[(size_t)(b * M + m) * NSEG + seg] = (uint32_t)(base < CAP ? base : CAP);
  }
}

template <bool FULL>
__device__ __forceinline__ void fused_body(const float* __restrict__ mk,
                                           const float* __restrict__ qkp,
                                           const float* __restrict__ asq,
                                           uint32_t* __restrict__ cnt,
                                           uint2* __restrict__ pairs,
                                           int b, int seg, int mg0,
                                           float (&vv)[4][SEGN]) {
  const int t = threadIdx.x;
  const int l = t & 63, w = t >> 6;

  const int nl0 = w * 256 + 4 * l;
  const int nb  = seg * SEGN + nl0;
  const bool vld = FULL || (nb < N);

  const float* p = mk + (size_t)b * CK * N + nb;
  const float* qrow = qkp + (size_t)b * CK * MP + mg0;  // wave-uniform

  float4 acc[16];
#pragma unroll
  for (int m = 0; m < 16; ++m) acc[m] = make_float4(0.f, 0.f, 0.f, 0.f);

  auto ld = [&](const float* q) -> float4 {
    return vld ? *reinterpret_cast<const float4*>(q) : make_float4(0.f, 0.f, 0.f, 0.f);
  };
  auto fmastep = [&](const float4& kv, const float* __restrict__ qc) {
#pragma unroll
    for (int m = 0; m < 16; ++m) {
      const float qm = qc[m];  // uniform -> s_load / SGPR operand
      acc[m].x += kv.x * qm;
      acc[m].y += kv.y * qm;
      acc[m].z += kv.z * qm;
      acc[m].w += kv.w * qm;
    }
  };

  float4 kva = ld(p);
  float4 kvb = ld(p + N);
  const float* pn = p + 2 * (size_t)N;
#pragma unroll 2
  for (int c = 0; c < CK - 2; ++c) {
    const float4 kvn = ld(pn);
    pn += N;
    fmastep(kva, qrow + (size_t)c * MP);
    kva = kvb;
    kvb = kvn;
  }
  fmastep(kva, qrow + (size_t)(CK - 2) * MP);
  fmastep(kvb, qrow + (size_t)(CK - 1) * MP);

  float4 sq4 = make_float4(0.f, 0.f, 0.f, 0.f);
  if (vld) sq4 = *reinterpret_cast<const float4*>(asq + (size_t)b * N + nb);

  const uint64_t lmlt = (1ull << l) - 1ull;

#pragma unroll
  for (int r = 0; r < 4; ++r) {
#pragma unroll
    for (int mj = 0; mj < 4; ++mj) {
      const float4 a = acc[4 * r + mj];  // static indices (rule #20)
      float4 vr;
      vr.x = (2.f * a.x - sq4.x) * 0.125f;
      vr.y = (2.f * a.y - sq4.y) * 0.125f;
      vr.z = (2.f * a.z - sq4.z) * 0.125f;
      vr.w = (2.f * a.w - sq4.w) * 0.125f;
      if (!FULL && !vld) vr = make_float4(-FLT_MAX, -FLT_MAX, -FLT_MAX, -FLT_MAX);
      *reinterpret_cast<float4*>(&vv[mj][nl0]) = vr;
    }
    __syncthreads();
    emit_round<FULL>(r, b, seg, mg0, l, w, lmlt, cnt, pairs, vv);
    __syncthreads();
  }
}

// K2+K0 combined: blocks [0,NWG) run fused (XCD-swizzled); blocks [NWG,
// NWG+TRB) run the mv->mvT transpose. Transpose blocks dispatch last and fill
// the fused kernel's drain tail -> the 80 MB transpose hides under compute.
// Shared memory is a union (16640 B = max(transpose tile, vv)).
__global__ __launch_bounds__(256) void fused_tr_kernel(const float* __restrict__ mk,
                                                       const float* __restrict__ qkp,
                                                       const float* __restrict__ asq,
                                                       uint32_t* __restrict__ cnt,
                                                       uint2* __restrict__ pairs,
                                                       const float* __restrict__ mv,
                                                       float* __restrict__ mvT) {
  __shared__ __align__(16) float smem[64 * 65];  // 16640 B >= 4*SEGN*4

  if (blockIdx.x < NWG) {
    auto& vv = *reinterpret_cast<float(*)[4][SEGN]>(smem);
    // bijective XCD swizzle (m204): contiguous wgid chunk per XCD, mg fastest
    constexpr int NX = 8;
    constexpr int Q = NWG / NX, R = NWG % NX;  // 331, 4
    const int orig = blockIdx.x;
    const int xcd = orig & (NX - 1), idx = orig >> 3;
    const int wgid = (xcd < R ? xcd * (Q + 1) : R * (Q + 1) + (xcd - R) * Q) + idx;
    const int segb = wgid / MG;
    const int mg   = wgid - segb * MG;
    const int b    = segb / NSEG;
    const int seg  = segb - b * NSEG;
    if (seg != NSEG - 1)
      fused_body<true>(mk, qkp, asq, cnt, pairs, b, seg, mg * 16, vv);
    else
      fused_body<false>(mk, qkp, asq, cnt, pairs, b, seg, mg * 16, vv);
  } else {
    auto& tile = *reinterpret_cast<float(*)[64][65]>(smem);
    const int id = blockIdx.x - NWG;
    const int x = id % TXB;
    const int rem = id / TXB;
    const int y = rem % (CV / 64);
    const int b = rem / (CV / 64);
    const int n0 = x * 64, c0 = y * 64;
    const int tx = threadIdx.x & 63, ty = threadIdx.x >> 6;
    for (int r = ty; r < 64; r += 4) {
      int c = c0 + r, n = n0 + tx;
      tile[r][tx] = (n < N) ? mv[((size_t)b * CV + c) * N + n] : 0.f;
    }
    __syncthreads();
    for (int r = ty; r < 64; r += 4) {
      int n = n0 + r, c = c0 + tx;
      if (n < N) mvT[((size_t)b * N + n) * CV + c] = tile[tx][r];
    }
  }
}

// K3: merge candidates -> exact global top-20 + softmax + fused gather.
// Compacted: prefix-sum the 13 segment counts, load ONLY the ~310 valid
// pairs (same candidate set; dead-slot reads eliminated). Histogram replicas
// 16 -> 4 (LDS zeroing 68 KB -> 17 KB per block; contention trivial at ~310
// adds). Radix logic, min-index tie-break, softmax, gather bit-identical.
__global__ __launch_bounds__(256) void merge_topk_gather(const uint32_t* __restrict__ cnt,
                                                         const uint2* __restrict__ pairs,
                                                         const float* __restrict__ mvT,
                                                         float* __restrict__ outT) {
  const int m = blockIdx.x, b = blockIdx.y;
  const int t = threadIdx.x;
  const int bm = b * M + m;

  __shared__ uint32_t sbase[NSEG + 1];
  constexpr int HP = 268;  // 1072B rows: 16B-aligned, non-pow2 bank offset
  __shared__ int hist[4][HP];
  __shared__ int s_digit, s_before;
  __shared__ int wn[K];
  __shared__ uint32_t wk[K];
  __shared__ float sw[K];
  __shared__ int gcnt, ecnt, s_last;
  __shared__ int ebuf[K];
  __shared__ int rmin4[4];

  if (t < NSEG) sbase[t + 1] = cnt[(size_t)bm * NSEG + t];
  __syncthreads();
  if (t == 0) {
    sbase[0] = 0;
    uint32_t a = 0;
    for (int s = 0; s < NSEG; ++s) { a += sbase[s + 1]; sbase[s + 1] = a; }
  }
  __syncthreads();
  const int Tn = (int)sbase[NSEG];  // total valid candidates (>= K, <= 832)

  // compact load: element i lives in segment s with sbase[s] <= i < sbase[s+1]
  uint32_t k[JC];
  uint32_t nn[JC];
#pragma unroll
  for (int j = 0; j < JC; ++j) {
    int i = t + (j << 8);
    if (i < Tn) {
      int s = 0;
      while ((int)sbase[s + 1] <= i) ++s;  // <= 13 iters
      uint2 pr = pairs[((size_t)bm * NSEG + s) * CAP + (i - (int)sbase[s])];
      k[j] = pr.x;
      nn[j] = pr.y;
    } else {
      k[j] = 0u;   // sorts below every real key (f2k(finite) > 0)
      nn[j] = 0u;
    }
  }

  int before = 0;
  uint32_t pref = 0;
  const int w = t >> 6;
  int* myhist = &hist[w][0];

  for (int p = 0; p < 4; ++p) {
    const int s = 24 - 8 * p;
    for (int i = t; i < 4 * HP; i += 256) ((int*)hist)[i] = 0;
    __syncthreads();
    const int shHi = (p == 0) ? 0 : (s + 8);
#pragma unroll
    for (int j = 0; j < JC; ++j) {
      uint32_t key = k[j];
      bool act = (p == 0) || ((key >> shHi) == pref);
      if (act) atomicAdd(&myhist[(key >> s) & 255], 1);
    }
    __syncthreads();
    if (t < 64) {
      int d = 4 * t;
      int4 g = make_int4(0, 0, 0, 0);
#pragma unroll
      for (int ww = 0; ww < 4; ++ww) {
        int4 h = *reinterpret_cast<int4*>(&hist[ww][d]);
        g.x += h.x; g.y += h.y; g.z += h.z; g.w += h.w;
      }
      int sl = g.x + g.y + g.z + g.w;
      int sfx = sl;
#pragma unroll
      for (int off = 1; off < 64; off <<= 1) {
        int o = __shfl_down(sfx, off);
        sfx += (t + off < 64) ? o : 0;
      }
      int above = sfx - sl;
      int rem = K - before;
      if (above < rem && rem <= sfx) {  // boundary digit in my 4-digit group
        int cum = above, ds;
        if (cum + g.w >= rem) ds = 3;
        else { cum += g.w;
          if (cum + g.z >= rem) ds = 2;
          else { cum += g.z;
            if (cum + g.y >= rem) ds = 1;
            else { cum += g.y; ds = 0; } } }
        s_digit = 4 * t + ds;
        s_before = before + cum;
      }
    }
    __syncthreads();
    pref = (pref << 8) | (uint32_t)s_digit;
    before = s_before;
  }

  const uint32_t thr = pref;
  const int need = K - before;
  if (t == 0) { gcnt = 0; ecnt = 0; }
  __syncthreads();
#pragma unroll
  for (int j = 0; j < JC; ++j) {
    uint32_t key = k[j];
    if (key > thr) {
      int q = atomicAdd(&gcnt, 1);
      wn[q] = (int)nn[j]; wk[q] = key;
    } else if (key == thr) {
      int q = atomicAdd(&ecnt, 1);
      if (q < K) ebuf[q] = (int)nn[j];
    }
  }
  __syncthreads();
  if (ecnt == need) {
    if (t < need) { wn[before + t] = ebuf[t]; wk[before + t] = thr; }
  } else {
    // rare boundary tie: pick `need` smallest indices among key == thr
    int last = -1;
    for (int r = 0; r < need; ++r) {
      int loc = INT_MAX;
#pragma unroll
      for (int j = 0; j < JC; ++j) {
        int n = (int)nn[j];
        if (k[j] == thr && n > last && n < loc) loc = n;
      }
#pragma unroll
      for (int off = 1; off < 64; off <<= 1) loc = min(loc, __shfl_xor(loc, off));
      if ((t & 63) == 0) rmin4[t >> 6] = loc;
      __syncthreads();
      if (t == 0) {
        int mn = min(min(rmin4[0], rmin4[1]), min(rmin4[2], rmin4[3]));
        wn[before + r] = mn; wk[before + r] = thr; s_last = mn;
      }
      __syncthreads();
      last = s_last;
    }
  }
  __syncthreads();

  // softmax over the K winners (wave 0)
  if (t < 64) {
    float v = (t < K) ? k2f(wk[t]) : -FLT_MAX;
    float mx = v;
#pragma unroll
    for (int off = 1; off < 64; off <<= 1) mx = fmaxf(mx, __shfl_xor(mx, off));
    float e = (t < K) ? expf(v - mx) : 0.f;
    float ss = e;
#pragma unroll
    for (int off = 1; off < 64; off <<= 1) ss += __shfl_xor(ss, off);
    if (t < K) sw[t] = e / ss;
  }
  __syncthreads();

  // fused gather: outT[b][m][c] = sum_j sw[j] * mvT[b][wn[j]][c]  (float4 rows)
  if (t < CV / 4) {
    const float4* tb4 = reinterpret_cast<const float4*>(mvT + (size_t)b * N * CV);
    float4 s4 = make_float4(0.f, 0.f, 0.f, 0.f);
#pragma unroll
    for (int j = 0; j < K; ++j) {
      float wj = sw[j];
      float4 vv4 = tb4[(size_t)wn[j] * (CV / 4) + t];
      s4.x += wj * vv4.x; s4.y += wj * vv4.y; s4.z += wj * vv4.z; s4.w += wj * vv4.w;
    }
    reinterpret_cast<float4*>(outT + ((size_t)b * M + m) * CV)[t] = s4;
  }
}

}  // namespace

extern "C" void kernel_launch(void* const* d_in, const int* in_sizes, int n_in,
                              void* d_out, int out_size, void* d_ws, size_t ws_size,
                              hipStream_t stream) {
  const float* mk = (const float*)d_in[0];
  const float* qk = (const float*)d_in[1];
  const float* mv = (const float*)d_in[2];
  float* out = (float*)d_out;

  char* w = (char*)d_ws;
  float* asq = (float*)w;
  size_t o = (size_t)B * N * sizeof(float);                 // 103,680 B
  float* mvT = (float*)(w + o);
  o += (size_t)B * N * CV * sizeof(float);                  // +39,813,120 B
  float* outT = (float*)(w + o);
  o += (size_t)B * M * CV * sizeof(float);                  // +4,976,640 B
  uint32_t* cnt = (uint32_t*)(w + o);
  o += (size_t)B * M * NSEG * sizeof(uint32_t);             // +168,480 B
  uint2* pairs = (uint2*)(w + o);
  o += (size_t)B * M * NSEG * CAP * sizeof(uint2);          // +21,565,440 B
  float* qkp = (float*)(w + o);
  o += (size_t)B * CK * MP * sizeof(float);                 // +835,584 B (total ~67.5 MB)

  // 4 launches (was 6): prep (asq+qkpad) -> fused+mvT-transpose -> merge -> out-transpose
  prep_kernel<<<ASQB + QKPB, 256, 0, stream>>>(mk, qk, asq, qkp);
  fused_tr_kernel<<<NWG + TRB, 256, 0, stream>>>(mk, qkp, asq, cnt, pairs, mv, mvT);
  merge_topk_gather<<<dim3(M, B), 256, 0, stream>>>(cnt, pairs, mvT, outT);
  transpose_out_kernel<<<dim3((M + 63) / 64, CV / 64, B), 256, 0, stream>>>(outT, out);
}